// Round 1
// baseline (5333.185 us; speedup 1.0000x reference)
//
#include <hip/hip_runtime.h>

#define BB 32
#define TT 512
#define DD 512
#define HH 1024
#define G4 4096   // 4*H
#define NWG 64
#define BLK 512
#define DPW 16    // h-dims per WG
#define HSLOT (BB * HH)   // one h ring slot (elements)

typedef __bf16 bf16x8 __attribute__((ext_vector_type(8)));
typedef float f32x4 __attribute__((ext_vector_type(4)));
typedef unsigned int u32x4 __attribute__((ext_vector_type(4)));
typedef unsigned short u16x4 __attribute__((ext_vector_type(4)));
typedef unsigned short u16x8 __attribute__((ext_vector_type(8)));
typedef unsigned long long u64;

__device__ __forceinline__ unsigned short f2b(float f) {
    unsigned u = __builtin_bit_cast(unsigned, f);
    u += 0x7fffu + ((u >> 16) & 1u);
    return (unsigned short)(u >> 16);
}
__device__ __forceinline__ float b2f(unsigned short s) {
    unsigned u = ((unsigned)s) << 16;
    return __builtin_bit_cast(float, u);
}

// ---------- Kernel 1: xp = bf16( X[B*T,D] @ Wi[D,4H] ), fp32 accum (unchanged) ----------
__global__ __launch_bounds__(256) void xproj_gemm(const float* __restrict__ X,
                                                  const float* __restrict__ Wi,
                                                  unsigned short* __restrict__ xp)
{
    __shared__ unsigned short As[64][40];   // [m][k]
    __shared__ unsigned short Bs[64][40];   // [n][k] transposed
    const int nb = G4 / 64;
    const int m0 = (blockIdx.x / nb) * 64;
    const int n0 = (blockIdx.x % nb) * 64;
    const int tid = threadIdx.x;
    const int w = tid >> 6;
    const int lane = tid & 63;
    const int q = lane >> 4;
    const int l16 = lane & 15;
    const int wm = (w >> 1) * 32, wn = (w & 1) * 32;

    const int ar = tid >> 2, ac = (tid & 3) * 8;
    const int bk = tid >> 3, bn = (tid & 7) * 8;

    f32x4 acc[2][2] = {};

    for (int k0 = 0; k0 < DD; k0 += 32) {
        const float* ap = X + (size_t)(m0 + ar) * DD + k0 + ac;
        float4 a0 = *(const float4*)ap;
        float4 a1 = *(const float4*)(ap + 4);
        unsigned short* as = &As[ar][ac];
        as[0]=f2b(a0.x); as[1]=f2b(a0.y); as[2]=f2b(a0.z); as[3]=f2b(a0.w);
        as[4]=f2b(a1.x); as[5]=f2b(a1.y); as[6]=f2b(a1.z); as[7]=f2b(a1.w);
        const float* bp = Wi + (size_t)(k0 + bk) * G4 + n0 + bn;
        float4 b0 = *(const float4*)bp;
        float4 b1 = *(const float4*)(bp + 4);
        Bs[bn+0][bk]=f2b(b0.x); Bs[bn+1][bk]=f2b(b0.y); Bs[bn+2][bk]=f2b(b0.z); Bs[bn+3][bk]=f2b(b0.w);
        Bs[bn+4][bk]=f2b(b1.x); Bs[bn+5][bk]=f2b(b1.y); Bs[bn+6][bk]=f2b(b1.z); Bs[bn+7][bk]=f2b(b1.w);
        __syncthreads();
        bf16x8 af0 = *(const bf16x8*)&As[wm + l16][q*8];
        bf16x8 af1 = *(const bf16x8*)&As[wm + 16 + l16][q*8];
        bf16x8 bfr0 = *(const bf16x8*)&Bs[wn + l16][q*8];
        bf16x8 bfr1 = *(const bf16x8*)&Bs[wn + 16 + l16][q*8];
        acc[0][0] = __builtin_amdgcn_mfma_f32_16x16x32_bf16(af0, bfr0, acc[0][0], 0,0,0);
        acc[0][1] = __builtin_amdgcn_mfma_f32_16x16x32_bf16(af0, bfr1, acc[0][1], 0,0,0);
        acc[1][0] = __builtin_amdgcn_mfma_f32_16x16x32_bf16(af1, bfr0, acc[1][0], 0,0,0);
        acc[1][1] = __builtin_amdgcn_mfma_f32_16x16x32_bf16(af1, bfr1, acc[1][1], 0,0,0);
        __syncthreads();
    }
    for (int i = 0; i < 2; i++) for (int j = 0; j < 2; j++) {
        int R = m0 + wm + i*16 + q*4;
        int C = n0 + wn + j*16 + l16;
        int b = R >> 9;
        int t = R & 511;
        int g = C >> 10;
        int hd = C & (HH - 1);
        u16x4 v;
        v.x = f2b(acc[i][j][0]); v.y = f2b(acc[i][j][1]);
        v.z = f2b(acc[i][j][2]); v.w = f2b(acc[i][j][3]);
        size_t off = (((size_t)(b * HH + hd) * (TT/8) + (t >> 3)) * 4 + g) * 8 + (t & 7);
        *(u16x4*)(xp + off) = v;
    }
}

// ---------- Kernel 2: persistent LSTM scan, two-half pipelined flag protocol ----------
// Batches 0-15 (half A) and 16-31 (half B) are INDEPENDENT recurrences sharing Wh.
// Per step: [pollA | MFMA-A | pointwise-A (waves 0-3) | publish fA] then the same for
// half B — each half's store-ack + flag-visibility + poll latency hides under the
// other half's compute. Sync via per-WG flag WORDS (plain sc1 stores, no atomic-RMW
// convoy); wave0 polls all 64 flags with one 64-lane load + __all; flags for the
// other half are presampled mid-phase so the steady-state poll is a register check.
// Wave layout (8 waves): kh = w&1 (K half), ct = w>>1 (gate 0..3). breg = 16 frags
// = 64 VGPR (half of before). Pointwise: waves 0-3 own bb<16, waves 4-7 own bb>=16
// (bb = tid>>4 unchanged).
__global__ __launch_bounds__(BLK, 1) void lstm_seq(
    const unsigned short* __restrict__ xp,      // [B][H][T/8][4][8] bf16
    const int* __restrict__ lengths,
    const float* __restrict__ c0,
    const float* __restrict__ h0,
    const float* __restrict__ Wh,
    const float* __restrict__ bias,
    float* __restrict__ out,                    // outputs[B,T,H] | c_fin[B,H] | h_fin[B,H]
    unsigned short* __restrict__ hbuf,          // [T+1][B*H] bf16 ring
    int* __restrict__ flags)                    // fA[0..63], fB[64..127]; host memset 0xff (=-1)
{
    __shared__ float gs[2][16][65];          // [khalf][batch-in-half][gate*16+dim]
    const int wg = blockIdx.x;
    const int tid = threadIdx.x;
    const int lane = tid & 63;
    const int w = tid >> 6;                  // 0..7
    const int q = lane >> 4, l16 = lane & 15;

    const int kh = w & 1;                    // K half
    const int ct = w >> 1;                   // gate 0..3 (16 cols each)
    const int kbase = kh * 512;

    // ---- one-time: 16 Wh B-fragments in registers (kh half x gate ct x 16 dims) ----
    bf16x8 breg[16];
    #pragma unroll
    for (int kk = 0; kk < 16; ++kk) {
        const int col = ct * HH + wg * DPW + l16;
        const int kb = kbase + kk*32 + q*8;
        u16x8 tv;
        #pragma unroll
        for (int e = 0; e < 8; ++e)
            tv[e] = f2b(Wh[(size_t)(kb + e) * G4 + col]);
        breg[kk] = __builtin_bit_cast(bf16x8, tv);
    }

    const int bb = tid >> 4, dd = tid & 15;  // bb<16 => half A (waves 0-3)
    const int gdim = wg * DPW + dd;
    float c   = c0[bb * HH + gdim];
    const int len = lengths[bb];
    const float bi  = bias[0*HH + gdim];
    const float bfg = bias[1*HH + gdim];
    const float bgv = bias[2*HH + gdim];
    const float bo  = bias[3*HH + gdim];
    const size_t xrow = ((size_t)bb * HH + gdim) * (TT/8) * 32;

    // h0 init: 128 threads store this WG's slice (32 b x 16 dims = 128 quads).
    if (tid < 128) {
        int b2 = tid >> 2, j = (tid & 3) * 4;
        const float* hp0 = h0 + (size_t)b2 * HH + wg * DPW + j;
        unsigned lo = (unsigned)f2b(hp0[0]) | ((unsigned)f2b(hp0[1]) << 16);
        unsigned hi = (unsigned)f2b(hp0[2]) | ((unsigned)f2b(hp0[3]) << 16);
        u64 v = (u64)lo | ((u64)hi << 32);
        __hip_atomic_store((u64*)(hbuf + (size_t)b2 * HH + wg * DPW + j), v,
                           __ATOMIC_RELAXED, __HIP_MEMORY_SCOPE_AGENT);
    }
    __syncthreads();                  // vmcnt(0): init stores acked at coherence point
    if (tid == 0) {
        __hip_atomic_store(&flags[wg],      0, __ATOMIC_RELAXED, __HIP_MEMORY_SCOPE_AGENT);
        __hip_atomic_store(&flags[64 + wg], 0, __ATOMIC_RELAXED, __HIP_MEMORY_SCOPE_AGENT);
    }

    // pointwise + h-publish for this thread's (bb, gdim); gs row = bb&15
    #define POINTWISE(T_, DT_)                                                              \
        {                                                                                   \
            const int wi = (DT_) >> 1, sh = ((DT_) & 1) * 16;                               \
            const int br = bb & 15;                                                         \
            float gi = gs[0][br][ 0 + dd] + gs[1][br][ 0 + dd] + b2f((unsigned short)(xq0[wi] >> sh)) + bi;  \
            float gf = gs[0][br][16 + dd] + gs[1][br][16 + dd] + b2f((unsigned short)(xq1[wi] >> sh)) + bfg; \
            float gg = gs[0][br][32 + dd] + gs[1][br][32 + dd] + b2f((unsigned short)(xq2[wi] >> sh)) + bgv; \
            float go = gs[0][br][48 + dd] + gs[1][br][48 + dd] + b2f((unsigned short)(xq3[wi] >> sh)) + bo;  \
            float si = 1.f / (1.f + __expf(-gi));                                           \
            float sf = 1.f / (1.f + __expf(-gf));                                           \
            float so = 1.f / (1.f + __expf(-go));                                           \
            float tg = 1.f - 2.f / (1.f + __expf(2.f * gg));                                \
            c = sf * c + si * tg;                                                           \
            float th = 1.f - 2.f / (1.f + __expf(2.f * c));                                 \
            float h = so * th;                                                              \
            hreg[DT_] = h;                                                                  \
            unsigned v = (unsigned)f2b(h);                                                  \
            unsigned p1 = __shfl_xor(v, 1);                                                 \
            unsigned pair = (dd & 1) ? (p1 | (v << 16)) : (v | (p1 << 16));                 \
            unsigned p2 = __shfl_xor(pair, 2);                                              \
            u64 quad = (dd & 2) ? ((u64)p2 | ((u64)pair << 32))                             \
                                : ((u64)pair | ((u64)p2 << 32));                            \
            if ((dd & 3) == 0)                                                              \
                __hip_atomic_store((u64*)(hbuf + (size_t)((T_) + 1) * HSLOT + (size_t)bb * HH + gdim), \
                                   quad, __ATOMIC_RELAXED, __HIP_MEMORY_SCOPE_AGENT);       \
            if ((T_) == len - 1) {                                                          \
                __builtin_nontemporal_store(c, &out[(size_t)BB*TT*HH + bb*HH + gdim]);      \
                __builtin_nontemporal_store(h, &out[(size_t)BB*TT*HH + (size_t)BB*HH + bb*HH + gdim]); \
            }                                                                               \
        }

    int preA = -1, preB = -1;        // wave0 presampled flag values
    for (int t0 = 0; t0 < TT; t0 += 8) {
        const unsigned short* xc = xp + xrow + (size_t)(t0 >> 3) * 32;
        u32x4 xq0 = __builtin_nontemporal_load((const u32x4*)(xc + 0));
        u32x4 xq1 = __builtin_nontemporal_load((const u32x4*)(xc + 8));
        u32x4 xq2 = __builtin_nontemporal_load((const u32x4*)(xc + 16));
        u32x4 xq3 = __builtin_nontemporal_load((const u32x4*)(xc + 24));
        float hreg[8];
        #pragma unroll
        for (int dt = 0; dt < 8; ++dt) {
            const int t = t0 + dt;
            // ================= phase A (batches 0-15) =================
            if (w == 0) {
                int v = preA;
                while (!__all(v >= t))
                    v = __hip_atomic_load(&flags[lane], __ATOMIC_RELAXED, __HIP_MEMORY_SCOPE_AGENT);
            }
            __syncthreads();                                            // b1
            {
                const unsigned short* ha = hbuf + (size_t)t * HSLOT
                                         + (size_t)l16 * HH + kbase + q*8;
                f32x4 acc = {0.f,0.f,0.f,0.f};
                #pragma unroll
                for (int kk = 0; kk < 16; ++kk) {
                    bf16x8 a = *(const bf16x8*)(ha + kk*32);            // plain cached (L1-shared across waves)
                    acc = __builtin_amdgcn_mfma_f32_16x16x32_bf16(a, breg[kk], acc, 0,0,0);
                }
                #pragma unroll
                for (int r = 0; r < 4; ++r)
                    gs[kh][q*4 + r][ct*16 + l16] = acc[r];
            }
            __syncthreads();                                            // b2
            if (w == 0)      // presample half-B flags; latency hides under A pointwise
                preB = __hip_atomic_load(&flags[64 + lane], __ATOMIC_RELAXED, __HIP_MEMORY_SCOPE_AGENT);
            if (bb < 16) POINTWISE(t, dt)
            __syncthreads();                                            // b3: vmcnt(0) acks A h-stores
            if (tid == 0)    // publish A slot t+1 (plain store, no RMW)
                __hip_atomic_store(&flags[wg], t + 1, __ATOMIC_RELAXED, __HIP_MEMORY_SCOPE_AGENT);
            // ================= phase B (batches 16-31) =================
            if (w == 0) {
                int v = preB;
                while (!__all(v >= t))
                    v = __hip_atomic_load(&flags[64 + lane], __ATOMIC_RELAXED, __HIP_MEMORY_SCOPE_AGENT);
            }
            __syncthreads();                                            // b4
            {
                const unsigned short* ha = hbuf + (size_t)t * HSLOT
                                         + (size_t)(16 + l16) * HH + kbase + q*8;
                f32x4 acc = {0.f,0.f,0.f,0.f};
                #pragma unroll
                for (int kk = 0; kk < 16; ++kk) {
                    bf16x8 a = *(const bf16x8*)(ha + kk*32);
                    acc = __builtin_amdgcn_mfma_f32_16x16x32_bf16(a, breg[kk], acc, 0,0,0);
                }
                #pragma unroll
                for (int r = 0; r < 4; ++r)
                    gs[kh][q*4 + r][ct*16 + l16] = acc[r];
            }
            __syncthreads();                                            // b5
            if (w == 0)      // presample half-A flags for step t+1
                preA = __hip_atomic_load(&flags[lane], __ATOMIC_RELAXED, __HIP_MEMORY_SCOPE_AGENT);
            if (bb >= 16) POINTWISE(t, dt)
            __syncthreads();                                            // b6: vmcnt(0) acks B h-stores
            if (tid == 0)    // publish B slot t+1
                __hip_atomic_store(&flags[64 + wg], t + 1, __ATOMIC_RELAXED, __HIP_MEMORY_SCOPE_AGENT);
        }
        // Flush 8 buffered h outputs; acks drain during subsequent polls/barriers.
        #pragma unroll
        for (int j = 0; j < 8; ++j)
            __builtin_nontemporal_store(hreg[j], &out[((size_t)bb * TT + t0 + j) * HH + gdim]);
    }
    #undef POINTWISE
}

extern "C" void kernel_launch(void* const* d_in, const int* in_sizes, int n_in,
                              void* d_out, int out_size, void* d_ws, size_t ws_size,
                              hipStream_t stream)
{
    const float* X    = (const float*)d_in[0];
    const int*   lens = (const int*)d_in[1];
    const float* c0   = (const float*)d_in[2];
    const float* h0   = (const float*)d_in[3];
    const float* Wi   = (const float*)d_in[4];
    const float* Wh   = (const float*)d_in[5];
    const float* bias = (const float*)d_in[6];
    float* out = (float*)d_out;

    // ws layout: xp bf16 [B][H][T/8][4][8] (134.2 MB) | hbuf ring bf16 [T+1][B*H]
    //            (33.6 MB) | flags int[128] (fA[64] | fB[64]), init -1
    unsigned short* xp   = (unsigned short*)d_ws;
    unsigned short* hbuf = xp + (size_t)BB * HH * TT * 4;
    int*            flags = (int*)(hbuf + (size_t)(TT + 1) * HSLOT);

    (void)hipMemsetAsync(flags, 0xff, sizeof(int) * 128, stream);

    xproj_gemm<<<dim3((BB*TT/64) * (G4/64)), dim3(256), 0, stream>>>(X, Wi, xp);

    const unsigned short* xp_c = xp;
    unsigned short* hbuf_p = hbuf;
    int* flags_p = flags;
    void* args[9];
    args[0] = (void*)&xp_c;
    args[1] = (void*)&lens;
    args[2] = (void*)&c0;
    args[3] = (void*)&h0;
    args[4] = (void*)&Wh;
    args[5] = (void*)&bias;
    args[6] = (void*)&out;
    args[7] = (void*)&hbuf_p;
    args[8] = (void*)&flags_p;
    (void)hipLaunchCooperativeKernel((void*)lstm_seq, dim3(NWG), dim3(BLK), args, 0, stream);
}